// Round 20
// baseline (189.817 us; speedup 1.0000x reference)
//
#include <hip/hip_runtime.h>

typedef unsigned short u16;
typedef unsigned int u32;
typedef __attribute__((ext_vector_type(8))) short bf16x8;
typedef __attribute__((ext_vector_type(4))) float f32x4;

#define CAP 2048           // records per 128-node bucket (mean ~1534, 13-sigma margin)
#define NBMAX 1024         // supports n <= 131072

__device__ __forceinline__ unsigned short f2bf(float f) {
    unsigned int u = __float_as_uint(f);
    unsigned int r = (u + 0x7FFFu + ((u >> 16) & 1u)) >> 16;   // round-to-nearest-even
    return (unsigned short)r;
}
__device__ __forceinline__ float bf2f(unsigned short h) {
    return __uint_as_float((unsigned int)h << 16);
}
__device__ __forceinline__ float blo(u32 u) { return __uint_as_float(u << 16); }
__device__ __forceinline__ float bhi(u32 u) { return __uint_as_float(u & 0xffff0000u); }

// Merged preprocessing: 40 blocks x 256 threads.
//  b in [0,4):  zero cursor (nb ints) ; b==0 also zeroes the pad row of ts
//  b in [4,36): Wp1 -> fragment-order bf16 (128 regions, 4/block)
//  b in [36,38): W1 -> split hi/lo fragment order (8 regions, 4/block)
//  b in [38,40): W2 -> split hi/lo fragment order
__global__ void prep_kernel(int* __restrict__ cursor, int nb, u16* __restrict__ zrow,
                            const float* __restrict__ Wp1, u16* __restrict__ Whi,
                            const float* __restrict__ W1, u16* __restrict__ W1hi, u16* __restrict__ W1lo,
                            const float* __restrict__ W2, u16* __restrict__ W2hi, u16* __restrict__ W2lo) {
    int b = blockIdx.x, tid = threadIdx.x;
    if (b < 4) {
        int i = b * 256 + tid;
        if (i < nb) cursor[i] = 0;
        if (b == 0 && tid < 64) zrow[tid] = 0;
        return;
    }
    if (b < 36) {
        int reg = (b - 4) * 4 + (tid >> 6);    // 0..127 = t*4 + s
        int t = reg >> 2, s = reg & 3;
        int lane = tid & 63;
        int col = t * 16 + (lane & 15);
        int k0 = s * 32 + (lane >> 4) * 8;
        unsigned short hv[8];
        #pragma unroll
        for (int i = 0; i < 8; ++i) hv[i] = f2bf(Wp1[(size_t)(k0 + i) * 512 + col]);
        size_t base = ((size_t)reg * 64 + lane) * 8;
        #pragma unroll
        for (int i = 0; i < 8; ++i) Whi[base + i] = hv[i];
        return;
    }
    {
        const float* W = (b < 38) ? W1 : W2;
        u16* Whi64 = (b < 38) ? W1hi : W2hi;
        u16* Wlo64 = (b < 38) ? W1lo : W2lo;
        int reg = ((b - 36) & 1) * 4 + (tid >> 6);   // 0..7
        int ct = reg >> 1, s = reg & 1;
        int lane = tid & 63;
        int col = ct * 16 + (lane & 15);
        int k0 = s * 32 + (lane >> 4) * 8;
        size_t base = ((size_t)reg * 64 + lane) * 8;
        #pragma unroll
        for (int i = 0; i < 8; ++i) {
            float v = W[(size_t)(k0 + i) * 64 + col];
            unsigned short hv = f2bf(v);
            Whi64[base + i] = hv;
            Wlo64[base + i] = f2bf(v - bf2f(hv));
        }
    }
}

// Bin edges into 128-node dst-buckets; chunk of 4096 edges counting-sorted in LDS
// so global record writes are bucket-grouped runs (no 64B/4B write amplification).
__global__ void binfill_kernel(const int* __restrict__ src, const int* __restrict__ dst,
                               int* __restrict__ cursor, u32* __restrict__ records,
                               int e, int nb) {
    __shared__ int h[NBMAX];
    __shared__ int coff[NBMAX];
    __shared__ int hc[NBMAX];
    __shared__ int gbase[NBMAX];
    __shared__ int partial[256];
    __shared__ u32 rec_s[4096];
    __shared__ unsigned short bkt_s[4096];
    int tid = threadIdx.x;
    int base = blockIdx.x * 4096;

    for (int i = tid; i < nb; i += 256) h[i] = 0;
    __syncthreads();

    u32 myrec[16];
    int myb[16];
    #pragma unroll
    for (int j = 0; j < 16; ++j) {
        int idx = base + j * 256 + tid;
        myb[j] = -1; myrec[j] = 0;
        if (idx < e) {
            int d = dst[idx], s = src[idx];
            myb[j] = d >> 7;
            myrec[j] = ((u32)s << 7) | (u32)(d & 127);
            atomicAdd(&h[myb[j]], 1);
        }
    }
    __syncthreads();

    // exclusive scan of h[0..nb) (4 buckets/thread), reserve global ranges
    int b0 = tid * 4;
    int c0 = (b0 + 0 < nb) ? h[b0 + 0] : 0;
    int c1 = (b0 + 1 < nb) ? h[b0 + 1] : 0;
    int c2 = (b0 + 2 < nb) ? h[b0 + 2] : 0;
    int c3 = (b0 + 3 < nb) ? h[b0 + 3] : 0;
    int tot = c0 + c1 + c2 + c3;
    partial[tid] = tot;
    __syncthreads();
    for (int off = 1; off < 256; off <<= 1) {
        int t = (tid >= off) ? partial[tid - off] : 0;
        __syncthreads();
        partial[tid] += t;
        __syncthreads();
    }
    int excl = partial[tid] - tot;
    int p0 = excl, p1 = excl + c0, p2 = excl + c0 + c1, p3 = excl + c0 + c1 + c2;
    if (b0 + 0 < nb) { coff[b0 + 0] = p0; hc[b0 + 0] = p0; if (c0) gbase[b0 + 0] = atomicAdd(&cursor[b0 + 0], c0); }
    if (b0 + 1 < nb) { coff[b0 + 1] = p1; hc[b0 + 1] = p1; if (c1) gbase[b0 + 1] = atomicAdd(&cursor[b0 + 1], c1); }
    if (b0 + 2 < nb) { coff[b0 + 2] = p2; hc[b0 + 2] = p2; if (c2) gbase[b0 + 2] = atomicAdd(&cursor[b0 + 2], c2); }
    if (b0 + 3 < nb) { coff[b0 + 3] = p3; hc[b0 + 3] = p3; if (c3) gbase[b0 + 3] = atomicAdd(&cursor[b0 + 3], c3); }
    __syncthreads();

    // place records into LDS in bucket-sorted order
    #pragma unroll
    for (int j = 0; j < 16; ++j) {
        if (myb[j] >= 0) {
            int p = atomicAdd(&hc[myb[j]], 1);
            rec_s[p] = myrec[j];
            bkt_s[p] = (unsigned short)myb[j];
        }
    }
    __syncthreads();

    // grouped write-out: consecutive p within a bucket -> consecutive global dest
    int totv = min(4096, e - base);
    #pragma unroll
    for (int j = 0; j < 16; ++j) {
        int p = tid + j * 256;
        if (p < totv) {
            int b = bkt_s[p];
            int pos = gbase[b] + (p - coff[b]);
            if (pos < CAP) records[(size_t)b * CAP + pos] = rec_s[p];
        }
    }
}

// Per bucket: node-sort records into CSR (within the bucket's CAP window),
// emit offs/end/dinv. Reads & writes confined to ~8KB windows -> no amplification.
__global__ void csr_sort_kernel(const u32* __restrict__ records, const int* __restrict__ cursor,
                                int* __restrict__ csr, int* __restrict__ offs, int* __restrict__ endo,
                                float* __restrict__ dinv, int n) {
    __shared__ u32 rec_s[CAP];
    __shared__ int h[128], hx[128], hc[128];
    int tid = threadIdx.x, b = blockIdx.x;
    int cnt = min(cursor[b], CAP);
    const u32* rp = records + (size_t)b * CAP;
    if (tid < 128) h[tid] = 0;
    __syncthreads();
    for (int j = tid; j < cnt; j += 256) {
        u32 r = rp[j];
        rec_s[j] = r;
        atomicAdd(&h[r & 127], 1);
    }
    __syncthreads();
    if (tid < 128) hx[tid] = h[tid];
    __syncthreads();
    for (int off = 1; off < 128; off <<= 1) {
        int t = (tid < 128 && tid >= off) ? hx[tid - off] : 0;
        __syncthreads();
        if (tid < 128) hx[tid] += t;
        __syncthreads();
    }
    if (tid < 128) {
        int excl = hx[tid] - h[tid];
        hc[tid] = excl;
        int g = b * 128 + tid;
        if (g < n) {
            offs[g] = b * CAP + excl;
            endo[g] = b * CAP + excl + h[tid];
            dinv[g] = rsqrtf((float)(1 + h[tid]));
        }
    }
    __syncthreads();
    for (int j = tid; j < cnt; j += 256) {
        u32 r = rec_s[j];
        int p = atomicAdd(&hc[r & 127], 1);
        csr[(size_t)b * CAP + p] = (int)(r >> 7);
    }
}

// ts[node][c] = bf16( (in[node] @ W)[c] * dinv[node] ) via MFMA, fragment-direct.
// Wave = 32 nodes (2 row-tiles): latency-bound kernel, maximize wave count.
// f32in path additionally stores its A fragments (x bf16) to Axh cols 64..127.
__launch_bounds__(256, 2)
__global__ void matmul64_mfma_kernel(const float* __restrict__ inF, const u16* __restrict__ inB,
                                     const u16* __restrict__ Whi, const u16* __restrict__ Wlo,
                                     const float* __restrict__ dinv, u16* __restrict__ out,
                                     u16* __restrict__ Axh, int n, int f32in) {
    int tid = threadIdx.x;
    int wave = tid >> 6, lane = tid & 63;
    int l15 = lane & 15, lg = lane >> 4;
    int node0 = blockIdx.x * 128 + wave * 32;

    // A fragments: 2 row-tiles x 2 ksteps
    bf16x8 a[2][2];
    #pragma unroll
    for (int rt = 0; rt < 2; ++rt)
        #pragma unroll
        for (int s = 0; s < 2; ++s) {
            int row = node0 + rt * 16 + l15;
            bf16x8 av = (bf16x8){0, 0, 0, 0, 0, 0, 0, 0};
            if (row < n) {
                if (f32in) {
                    const float* p = inF + (size_t)row * 64 + s * 32 + lg * 8;
                    float4 v0 = *(const float4*)p;
                    float4 v1 = *(const float4*)(p + 4);
                    av[0] = (short)f2bf(v0.x); av[1] = (short)f2bf(v0.y);
                    av[2] = (short)f2bf(v0.z); av[3] = (short)f2bf(v0.w);
                    av[4] = (short)f2bf(v1.x); av[5] = (short)f2bf(v1.y);
                    av[6] = (short)f2bf(v1.z); av[7] = (short)f2bf(v1.w);
                } else {
                    av = *(const bf16x8*)(inB + (size_t)row * 64 + s * 32 + lg * 8);
                }
            }
            a[rt][s] = av;
        }

    // fold of xcvt: x fragments ARE the A cols 64..127 fragments; per-lane store
    // address is contiguous: ((nt*4 + 2 + s)*64 + lane)*8
    if (f32in) {
        #pragma unroll
        for (int rt = 0; rt < 2; ++rt)
            #pragma unroll
            for (int s = 0; s < 2; ++s) {
                size_t reg = ((size_t)((node0 >> 4) + rt) * 4 + 2 + s);
                *(bf16x8*)(Axh + (reg * 64 + lane) * 8) = a[rt][s];
            }
    }

    // B fragments: 4 col-tiles x 2 ksteps, hi+lo
    bf16x8 bh[4][2], bl[4][2];
    #pragma unroll
    for (int ct = 0; ct < 4; ++ct)
        #pragma unroll
        for (int s = 0; s < 2; ++s) {
            size_t off = (((size_t)(ct * 2 + s)) * 64 + lane) * 8;
            bh[ct][s] = *(const bf16x8*)(Whi + off);
            bl[ct][s] = *(const bf16x8*)(Wlo + off);
        }

    f32x4 acc[2][4];
    #pragma unroll
    for (int rt = 0; rt < 2; ++rt)
        #pragma unroll
        for (int ct = 0; ct < 4; ++ct) acc[rt][ct] = (f32x4){0.f, 0.f, 0.f, 0.f};

    #pragma unroll
    for (int s = 0; s < 2; ++s)
        #pragma unroll
        for (int rt = 0; rt < 2; ++rt)
            #pragma unroll
            for (int ct = 0; ct < 4; ++ct) {
                acc[rt][ct] = __builtin_amdgcn_mfma_f32_16x16x32_bf16(a[rt][s], bh[ct][s], acc[rt][ct], 0, 0, 0);
                acc[rt][ct] = __builtin_amdgcn_mfma_f32_16x16x32_bf16(a[rt][s], bl[ct][s], acc[rt][ct], 0, 0, 0);
            }

    // epilogue: scale by dinv, cvt bf16, store (C layout: col=l&15, row=lg*4+r)
    #pragma unroll
    for (int rt = 0; rt < 2; ++rt)
        #pragma unroll
        for (int r = 0; r < 4; ++r) {
            int node = node0 + rt * 16 + lg * 4 + r;
            if (node < n) {
                float dv = dinv[node];
                #pragma unroll
                for (int ct = 0; ct < 4; ++ct)
                    out[(size_t)node * 64 + ct * 16 + l15] = f2bf(acc[rt][ct][r] * dv);
            }
        }
}

// Vectorized gather agg: one wave per node; lane handles features 4*(l&15)..+3;
// 4 lane-groups x 8 unrolled = 32 edges (8 independent gathers) in flight per
// iteration; tail lanes gather the pre-zeroed row n (no masking).
// Layer 1: relu, row-major bf16 out.
__global__ void agg4_csr_kernel(const int* __restrict__ csr, const int* __restrict__ offs,
                                const int* __restrict__ endo, const u16* __restrict__ ts,
                                const float* __restrict__ dinv, const float* __restrict__ bias,
                                u16* __restrict__ out, int n) {
    int node = blockIdx.x * 4 + (threadIdx.x >> 6);
    int lane = threadIdx.x & 63;
    int l15 = lane & 15, lg = lane >> 4;
    if (node >= n) return;
    int start = offs[node];
    int end = endo[node];
    const uint2* tsv = (const uint2*)ts;   // row = 16 uint2; row n is all-zero
    float a0 = 0.f, a1 = 0.f, a2 = 0.f, a3 = 0.f;
    for (int j = start; j < end; j += 64) {
        int cnt = min(64, end - j);
        int sidx = (lane < cnt) ? csr[j + lane] : n;   // tail -> zero row
        for (int jb = 0; jb < cnt; jb += 32) {
            int s0 = __shfl(sidx, jb + lg);
            int s1 = __shfl(sidx, jb + 4 + lg);
            int s2 = __shfl(sidx, jb + 8 + lg);
            int s3 = __shfl(sidx, jb + 12 + lg);
            int s4 = __shfl(sidx, jb + 16 + lg);
            int s5 = __shfl(sidx, jb + 20 + lg);
            int s6 = __shfl(sidx, jb + 24 + lg);
            int s7 = __shfl(sidx, jb + 28 + lg);
            uint2 w0 = tsv[(size_t)s0 * 16 + l15];
            uint2 w1 = tsv[(size_t)s1 * 16 + l15];
            uint2 w2 = tsv[(size_t)s2 * 16 + l15];
            uint2 w3 = tsv[(size_t)s3 * 16 + l15];
            uint2 w4 = tsv[(size_t)s4 * 16 + l15];
            uint2 w5 = tsv[(size_t)s5 * 16 + l15];
            uint2 w6 = tsv[(size_t)s6 * 16 + l15];
            uint2 w7 = tsv[(size_t)s7 * 16 + l15];
            a0 += ((blo(w0.x) + blo(w1.x)) + (blo(w2.x) + blo(w3.x)))
                + ((blo(w4.x) + blo(w5.x)) + (blo(w6.x) + blo(w7.x)));
            a1 += ((bhi(w0.x) + bhi(w1.x)) + (bhi(w2.x) + bhi(w3.x)))
                + ((bhi(w4.x) + bhi(w5.x)) + (bhi(w6.x) + bhi(w7.x)));
            a2 += ((blo(w0.y) + blo(w1.y)) + (blo(w2.y) + blo(w3.y)))
                + ((blo(w4.y) + blo(w5.y)) + (blo(w6.y) + blo(w7.y)));
            a3 += ((bhi(w0.y) + bhi(w1.y)) + (bhi(w2.y) + bhi(w3.y)))
                + ((bhi(w4.y) + bhi(w5.y)) + (bhi(w6.y) + bhi(w7.y)));
        }
    }
    a0 += __shfl_xor(a0, 16); a0 += __shfl_xor(a0, 32);
    a1 += __shfl_xor(a1, 16); a1 += __shfl_xor(a1, 32);
    a2 += __shfl_xor(a2, 16); a2 += __shfl_xor(a2, 32);
    a3 += __shfl_xor(a3, 16); a3 += __shfl_xor(a3, 32);
    uint2 sw = tsv[(size_t)node * 16 + l15];     // self-loop row
    a0 += blo(sw.x); a1 += bhi(sw.x); a2 += blo(sw.y); a3 += bhi(sw.y);
    float dv = dinv[node];
    float4 bv = *(const float4*)(bias + 4 * l15);
    float v0 = fmaxf(dv * a0 + bv.x, 0.f);
    float v1 = fmaxf(dv * a1 + bv.y, 0.f);
    float v2 = fmaxf(dv * a2 + bv.z, 0.f);
    float v3 = fmaxf(dv * a3 + bv.w, 0.f);
    if (lg == 0) {
        u32 p0 = ((u32)f2bf(v1) << 16) | (u32)f2bf(v0);
        u32 p1 = ((u32)f2bf(v3) << 16) | (u32)f2bf(v2);
        *(uint2*)(out + (size_t)node * 64 + l15 * 4) = make_uint2(p0, p1);
    }
}

// Layer 2 variant: no relu; writes bf16 in MFMA fragment order (A cols 0..63).
__global__ void agg4_csr_frag_kernel(const int* __restrict__ csr, const int* __restrict__ offs,
                                     const int* __restrict__ endo, const u16* __restrict__ ts,
                                     const float* __restrict__ dinv, const float* __restrict__ bias,
                                     u16* __restrict__ Ahi, int n) {
    int node = blockIdx.x * 4 + (threadIdx.x >> 6);
    int lane = threadIdx.x & 63;
    int l15 = lane & 15, lg = lane >> 4;
    if (node >= n) return;
    int start = offs[node];
    int end = endo[node];
    const uint2* tsv = (const uint2*)ts;
    float a0 = 0.f, a1 = 0.f, a2 = 0.f, a3 = 0.f;
    for (int j = start; j < end; j += 64) {
        int cnt = min(64, end - j);
        int sidx = (lane < cnt) ? csr[j + lane] : n;   // tail -> zero row
        for (int jb = 0; jb < cnt; jb += 32) {
            int s0 = __shfl(sidx, jb + lg);
            int s1 = __shfl(sidx, jb + 4 + lg);
            int s2 = __shfl(sidx, jb + 8 + lg);
            int s3 = __shfl(sidx, jb + 12 + lg);
            int s4 = __shfl(sidx, jb + 16 + lg);
            int s5 = __shfl(sidx, jb + 20 + lg);
            int s6 = __shfl(sidx, jb + 24 + lg);
            int s7 = __shfl(sidx, jb + 28 + lg);
            uint2 w0 = tsv[(size_t)s0 * 16 + l15];
            uint2 w1 = tsv[(size_t)s1 * 16 + l15];
            uint2 w2 = tsv[(size_t)s2 * 16 + l15];
            uint2 w3 = tsv[(size_t)s3 * 16 + l15];
            uint2 w4 = tsv[(size_t)s4 * 16 + l15];
            uint2 w5 = tsv[(size_t)s5 * 16 + l15];
            uint2 w6 = tsv[(size_t)s6 * 16 + l15];
            uint2 w7 = tsv[(size_t)s7 * 16 + l15];
            a0 += ((blo(w0.x) + blo(w1.x)) + (blo(w2.x) + blo(w3.x)))
                + ((blo(w4.x) + blo(w5.x)) + (blo(w6.x) + blo(w7.x)));
            a1 += ((bhi(w0.x) + bhi(w1.x)) + (bhi(w2.x) + bhi(w3.x)))
                + ((bhi(w4.x) + bhi(w5.x)) + (bhi(w6.x) + bhi(w7.x)));
            a2 += ((blo(w0.y) + blo(w1.y)) + (blo(w2.y) + blo(w3.y)))
                + ((blo(w4.y) + blo(w5.y)) + (blo(w6.y) + blo(w7.y)));
            a3 += ((bhi(w0.y) + bhi(w1.y)) + (bhi(w2.y) + bhi(w3.y)))
                + ((bhi(w4.y) + bhi(w5.y)) + (bhi(w6.y) + bhi(w7.y)));
        }
    }
    a0 += __shfl_xor(a0, 16); a0 += __shfl_xor(a0, 32);
    a1 += __shfl_xor(a1, 16); a1 += __shfl_xor(a1, 32);
    a2 += __shfl_xor(a2, 16); a2 += __shfl_xor(a2, 32);
    a3 += __shfl_xor(a3, 16); a3 += __shfl_xor(a3, 32);
    uint2 sw = tsv[(size_t)node * 16 + l15];
    a0 += blo(sw.x); a1 += bhi(sw.x); a2 += blo(sw.y); a3 += bhi(sw.y);
    float dv = dinv[node];
    float4 bv = *(const float4*)(bias + 4 * l15);
    float v0 = dv * a0 + bv.x;
    float v1 = dv * a1 + bv.y;
    float v2 = dv * a2 + bv.z;
    float v3 = dv * a3 + bv.w;
    if (lg == 0) {
        int nt = node >> 4, r15 = node & 15;
        size_t a = (((size_t)nt * 4 + (l15 >> 3)) * 64 + ((l15 >> 1) & 3) * 16 + r15) * 8 + 4 * (l15 & 1);
        u32 p0 = ((u32)f2bf(v1) << 16) | (u32)f2bf(v0);
        u32 p1 = ((u32)f2bf(v3) << 16) | (u32)f2bf(v2);
        *(uint2*)(Ahi + a) = make_uint2(p0, p1);
    }
}

__device__ __forceinline__ void loadW6(const u16* __restrict__ Whi,
                                       int t0, int s, int lane, bf16x8 (&bh)[4]) {
    #pragma unroll
    for (int ct = 0; ct < 4; ++ct) {
        size_t off = (((size_t)(t0 + ct) * 4 + s) * 64 + lane) * 8;
        bh[ct] = *(const bf16x8*)(Whi + off);
    }
}

// MLP head v6 (proven best; v7/v8/v9 all lost to occupancy or compiler W-remat):
// block = 256 nodes (4 waves x 64 nodes), all 512 cols.
// A bf16 in LDS (64 KB); W plain bf16 double-buffered from L2.
__launch_bounds__(256, 2)
__global__ void mlp_mfma6_kernel(const u16* __restrict__ Ahi, const u16* __restrict__ Whi,
                                 const float* __restrict__ bp1, const float* __restrict__ Wp2,
                                 const float* __restrict__ bp2, float* __restrict__ out, int n) {
    __shared__ __align__(16) u16 a_s[32768];    // 64 KB: 64 regions x 512 u16
    __shared__ __align__(16) float b1lds[512];
    __shared__ __align__(16) float w2lds[512 * 3];
    int tid = threadIdx.x;

    // stage A slice (contiguous in fragment-linear order)
    size_t gbase = (size_t)blockIdx.x * 32768;
    #pragma unroll
    for (int i = 0; i < 16; ++i) {
        int idx = i * 2048 + tid * 8;
        *(bf16x8*)&a_s[idx] = *(const bf16x8*)(Ahi + gbase + idx);
    }
    b1lds[tid] = bp1[tid];
    b1lds[tid + 256] = bp1[tid + 256];
    #pragma unroll
    for (int i = 0; i < 6; ++i) w2lds[tid + i * 256] = Wp2[tid + i * 256];
    __syncthreads();

    int wave = tid >> 6, lane = tid & 63;
    int l15 = lane & 15, l4 = lane >> 4;
    int node0 = blockIdx.x * 256 + wave * 64;

    float pr[4][4][3];
    #pragma unroll
    for (int rt = 0; rt < 4; ++rt)
        #pragma unroll
        for (int r = 0; r < 4; ++r) { pr[rt][r][0] = 0.f; pr[rt][r][1] = 0.f; pr[rt][r][2] = 0.f; }

    bf16x8 bhE[4], bhO[4];
    loadW6(Whi, 0, 0, lane, bhE);

#define MFMA_S(S, BH)                                                                      \
    do {                                                                                   \
        _Pragma("unroll")                                                                  \
        for (int rt = 0; rt < 4; ++rt) {                                                   \
            bf16x8 a = *(const bf16x8*)&a_s[(wave * 16 + rt * 4 + (S)) * 512 + lane * 8];  \
            _Pragma("unroll")                                                              \
            for (int ct = 0; ct < 4; ++ct)                                                 \
                acc[rt][ct] = __builtin_amdgcn_mfma_f32_16x16x32_bf16(a, BH[ct], acc[rt][ct], 0, 0, 0); \
        }                                                                                  \
    } while (0)

    for (int cg = 0; cg < 8; ++cg) {
        f32x4 acc[4][4];
        #pragma unroll
        for (int rt = 0; rt < 4; ++rt)
            #pragma unroll
            for (int ct = 0; ct < 4; ++ct) acc[rt][ct] = (f32x4){0.f, 0.f, 0.f, 0.f};

        int t0 = cg * 4;
        loadW6(Whi, t0, 1, lane, bhO);
        MFMA_S(0, bhE);
        loadW6(Whi, t0, 2, lane, bhE);
        MFMA_S(1, bhO);
        loadW6(Whi, t0, 3, lane, bhO);
        MFMA_S(2, bhE);
        loadW6(Whi, ((cg + 1) & 7) * 4, 0, lane, bhE);   // wraps to cg=0, harmless
        MFMA_S(3, bhO);

        // fold this col-group into per-lane partials
        #pragma unroll
        for (int ct = 0; ct < 4; ++ct) {
            int c = (t0 + ct) * 16 + l15;
            float b1v = b1lds[c];
            float w20 = w2lds[c * 3 + 0], w21 = w2lds[c * 3 + 1], w22 = w2lds[c * 3 + 2];
            #pragma unroll
            for (int rt = 0; rt < 4; ++rt)
                #pragma unroll
                for (int r = 0; r < 4; ++r) {
                    float h = fmaxf(acc[rt][ct][r] + b1v, 0.f);
                    pr[rt][r][0] = fmaf(h, w20, pr[rt][r][0]);
                    pr[rt][r][1] = fmaf(h, w21, pr[rt][r][1]);
                    pr[rt][r][2] = fmaf(h, w22, pr[rt][r][2]);
                }
        }
    }
#undef MFMA_S

    float c0 = bp2[0], c1 = bp2[1], c2 = bp2[2];
    #pragma unroll
    for (int rt = 0; rt < 4; ++rt)
        #pragma unroll
        for (int r = 0; r < 4; ++r)
            #pragma unroll
            for (int j = 0; j < 3; ++j) {
                float v = pr[rt][r][j];
                v += __shfl_xor(v, 1);
                v += __shfl_xor(v, 2);
                v += __shfl_xor(v, 4);
                v += __shfl_xor(v, 8);
                pr[rt][r][j] = v;
            }
    if (l15 == 0) {
        #pragma unroll
        for (int rt = 0; rt < 4; ++rt)
            #pragma unroll
            for (int r = 0; r < 4; ++r) {
                int node = node0 + rt * 16 + l4 * 4 + r;
                if (node < n) {
                    out[(size_t)node * 3 + 0] = pr[rt][r][0] + c0;
                    out[(size_t)node * 3 + 1] = pr[rt][r][1] + c1;
                    out[(size_t)node * 3 + 2] = pr[rt][r][2] + c2;
                }
            }
    }
}

extern "C" void kernel_launch(void* const* d_in, const int* in_sizes, int n_in,
                              void* d_out, int out_size, void* d_ws, size_t ws_size,
                              hipStream_t stream) {
    const float* x   = (const float*)d_in[0];
    const int*   ei  = (const int*)d_in[1];   // [2][E]
    const float* W1  = (const float*)d_in[2];
    const float* b1  = (const float*)d_in[3];
    const float* W2  = (const float*)d_in[4];
    const float* b2  = (const float*)d_in[5];
    const float* Wp1 = (const float*)d_in[6];
    const float* bp1 = (const float*)d_in[7];
    const float* Wp2 = (const float*)d_in[8];
    const float* bp2 = (const float*)d_in[9];
    float* out = (float*)d_out;

    const int n = in_sizes[0] / 64;
    const int e = in_sizes[1] / 2;
    const int pad_n = (n + 255) & ~255;      // mlp block = 256 nodes
    const int nb = (n + 127) >> 7;           // 128-node buckets
    const int* src = ei;
    const int* dst = ei + e;

    char* ws = (char*)d_ws;
    size_t o = 0;
    int* cursor = (int*)(ws + o);            o += ((size_t)nb * 4 + 511) & ~(size_t)511;
    int* offs   = (int*)(ws + o);            o += ((size_t)n * 4 + 511) & ~(size_t)511;
    int* endo   = (int*)(ws + o);            o += ((size_t)n * 4 + 511) & ~(size_t)511;
    float* dinv = (float*)(ws + o);          o += ((size_t)n * 4 + 511) & ~(size_t)511;
    u32* records = (u32*)(ws + o);           o += ((size_t)nb * CAP * 4 + 511) & ~(size_t)511;
    int* csr    = (int*)(ws + o);            o += ((size_t)nb * CAP * 4 + 511) & ~(size_t)511;
    u16* tsbuf  = (u16*)(ws + o);            o += ((size_t)(pad_n + 256) * 64 * 2 + 511) & ~(size_t)511;  // +1 zero row
    u16* h1b    = (u16*)(ws + o);            o += ((size_t)pad_n * 64 * 2 + 511) & ~(size_t)511;
    u16* Ahi    = (u16*)(ws + o);            o += ((size_t)pad_n * 128 * 2 + 511) & ~(size_t)511;
    u16* Whi    = (u16*)(ws + o);            o += 512 * 128 * 2;
    u16* W1hi   = (u16*)(ws + o);            o += 64 * 64 * 2;
    u16* W1lo   = (u16*)(ws + o);            o += 64 * 64 * 2;
    u16* W2hi   = (u16*)(ws + o);            o += 64 * 64 * 2;
    u16* W2lo   = (u16*)(ws + o);            o += 64 * 64 * 2;

    // ----- merged preprocessing: cursor/zrow zero + all weight conversions -----
    hipLaunchKernelGGL(prep_kernel, dim3(40), dim3(256), 0, stream,
                       cursor, nb, tsbuf + (size_t)n * 64,
                       Wp1, Whi, W1, W1hi, W1lo, W2, W2hi, W2lo);
    hipLaunchKernelGGL(binfill_kernel, dim3((e + 4095) / 4096), dim3(256), 0, stream,
                       src, dst, cursor, records, e, nb);
    hipLaunchKernelGGL(csr_sort_kernel, dim3(nb), dim3(256), 0, stream,
                       records, cursor, csr, offs, endo, dinv, n);

    // ----- GCN layer 1: ts1 = bf16((x @ W1) * dinv); also emits x -> Ahi cols 64..127 -----
    hipLaunchKernelGGL(matmul64_mfma_kernel, dim3(pad_n / 128), dim3(256), 0, stream,
                       x, (const u16*)nullptr, W1hi, W1lo, dinv, tsbuf, Ahi, n, 1);
    hipLaunchKernelGGL(agg4_csr_kernel, dim3((n + 3) / 4), dim3(256), 0, stream,
                       csr, offs, endo, tsbuf, dinv, b1, h1b, n);

    // ----- GCN layer 2: ts2 = bf16((h1 @ W2) * dinv); agg writes bf16 A cols 0..63 -----
    hipLaunchKernelGGL(matmul64_mfma_kernel, dim3(pad_n / 128), dim3(256), 0, stream,
                       (const float*)nullptr, h1b, W2hi, W2lo, dinv, tsbuf, (u16*)nullptr, n, 0);
    hipLaunchKernelGGL(agg4_csr_frag_kernel, dim3((n + 3) / 4), dim3(256), 0, stream,
                       csr, offs, endo, tsbuf, dinv, b2, Ahi, n);

    // ----- MLP head (LDS-A bf16, bf16 W, MFMA) -----
    hipLaunchKernelGGL(mlp_mfma6_kernel, dim3(pad_n / 256), dim3(256), 0, stream,
                       Ahi, Whi, bp1, Wp2, bp2, out, n);
}

// Round 21
// 173.980 us; speedup vs baseline: 1.0910x; 1.0910x over previous
//
#include <hip/hip_runtime.h>

typedef unsigned short u16;
typedef unsigned int u32;
typedef __attribute__((ext_vector_type(8))) short bf16x8;
typedef __attribute__((ext_vector_type(4))) float f32x4;

#define CAP 2048           // records per 128-node bucket (mean ~1534, 13-sigma margin)
#define NBMAX 1024         // supports n <= 131072

__device__ __forceinline__ unsigned short f2bf(float f) {
    unsigned int u = __float_as_uint(f);
    unsigned int r = (u + 0x7FFFu + ((u >> 16) & 1u)) >> 16;   // round-to-nearest-even
    return (unsigned short)r;
}
__device__ __forceinline__ float bf2f(unsigned short h) {
    return __uint_as_float((unsigned int)h << 16);
}
__device__ __forceinline__ float blo(u32 u) { return __uint_as_float(u << 16); }
__device__ __forceinline__ float bhi(u32 u) { return __uint_as_float(u & 0xffff0000u); }

// Merged preprocessing: 40 blocks x 256 threads.
//  b in [0,4):  zero cursor (nb ints) ; b==0 also zeroes the pad row of ts
//  b in [4,36): Wp1 -> fragment-order bf16 (128 regions, 4/block)
//  b in [36,38): W1 -> split hi/lo fragment order (8 regions, 4/block)
//  b in [38,40): W2 -> split hi/lo fragment order
__global__ void prep_kernel(int* __restrict__ cursor, int nb, u16* __restrict__ zrow,
                            const float* __restrict__ Wp1, u16* __restrict__ Whi,
                            const float* __restrict__ W1, u16* __restrict__ W1hi, u16* __restrict__ W1lo,
                            const float* __restrict__ W2, u16* __restrict__ W2hi, u16* __restrict__ W2lo) {
    int b = blockIdx.x, tid = threadIdx.x;
    if (b < 4) {
        int i = b * 256 + tid;
        if (i < nb) cursor[i] = 0;
        if (b == 0 && tid < 64) zrow[tid] = 0;
        return;
    }
    if (b < 36) {
        int reg = (b - 4) * 4 + (tid >> 6);    // 0..127 = t*4 + s
        int t = reg >> 2, s = reg & 3;
        int lane = tid & 63;
        int col = t * 16 + (lane & 15);
        int k0 = s * 32 + (lane >> 4) * 8;
        unsigned short hv[8];
        #pragma unroll
        for (int i = 0; i < 8; ++i) hv[i] = f2bf(Wp1[(size_t)(k0 + i) * 512 + col]);
        size_t base = ((size_t)reg * 64 + lane) * 8;
        #pragma unroll
        for (int i = 0; i < 8; ++i) Whi[base + i] = hv[i];
        return;
    }
    {
        const float* W = (b < 38) ? W1 : W2;
        u16* Whi64 = (b < 38) ? W1hi : W2hi;
        u16* Wlo64 = (b < 38) ? W1lo : W2lo;
        int reg = ((b - 36) & 1) * 4 + (tid >> 6);   // 0..7
        int ct = reg >> 1, s = reg & 1;
        int lane = tid & 63;
        int col = ct * 16 + (lane & 15);
        int k0 = s * 32 + (lane >> 4) * 8;
        size_t base = ((size_t)reg * 64 + lane) * 8;
        #pragma unroll
        for (int i = 0; i < 8; ++i) {
            float v = W[(size_t)(k0 + i) * 64 + col];
            unsigned short hv = f2bf(v);
            Whi64[base + i] = hv;
            Wlo64[base + i] = f2bf(v - bf2f(hv));
        }
    }
}

// Bin edges into 128-node dst-buckets; chunk of 4096 edges counting-sorted in LDS
// so global record writes are bucket-grouped runs (no 64B/4B write amplification).
__global__ void binfill_kernel(const int* __restrict__ src, const int* __restrict__ dst,
                               int* __restrict__ cursor, u32* __restrict__ records,
                               int e, int nb) {
    __shared__ int h[NBMAX];
    __shared__ int coff[NBMAX];
    __shared__ int hc[NBMAX];
    __shared__ int gbase[NBMAX];
    __shared__ int partial[256];
    __shared__ u32 rec_s[4096];
    __shared__ unsigned short bkt_s[4096];
    int tid = threadIdx.x;
    int base = blockIdx.x * 4096;

    for (int i = tid; i < nb; i += 256) h[i] = 0;
    __syncthreads();

    u32 myrec[16];
    int myb[16];
    #pragma unroll
    for (int j = 0; j < 16; ++j) {
        int idx = base + j * 256 + tid;
        myb[j] = -1; myrec[j] = 0;
        if (idx < e) {
            int d = dst[idx], s = src[idx];
            myb[j] = d >> 7;
            myrec[j] = ((u32)s << 7) | (u32)(d & 127);
            atomicAdd(&h[myb[j]], 1);
        }
    }
    __syncthreads();

    // exclusive scan of h[0..nb) (4 buckets/thread), reserve global ranges
    int b0 = tid * 4;
    int c0 = (b0 + 0 < nb) ? h[b0 + 0] : 0;
    int c1 = (b0 + 1 < nb) ? h[b0 + 1] : 0;
    int c2 = (b0 + 2 < nb) ? h[b0 + 2] : 0;
    int c3 = (b0 + 3 < nb) ? h[b0 + 3] : 0;
    int tot = c0 + c1 + c2 + c3;
    partial[tid] = tot;
    __syncthreads();
    for (int off = 1; off < 256; off <<= 1) {
        int t = (tid >= off) ? partial[tid - off] : 0;
        __syncthreads();
        partial[tid] += t;
        __syncthreads();
    }
    int excl = partial[tid] - tot;
    int p0 = excl, p1 = excl + c0, p2 = excl + c0 + c1, p3 = excl + c0 + c1 + c2;
    if (b0 + 0 < nb) { coff[b0 + 0] = p0; hc[b0 + 0] = p0; if (c0) gbase[b0 + 0] = atomicAdd(&cursor[b0 + 0], c0); }
    if (b0 + 1 < nb) { coff[b0 + 1] = p1; hc[b0 + 1] = p1; if (c1) gbase[b0 + 1] = atomicAdd(&cursor[b0 + 1], c1); }
    if (b0 + 2 < nb) { coff[b0 + 2] = p2; hc[b0 + 2] = p2; if (c2) gbase[b0 + 2] = atomicAdd(&cursor[b0 + 2], c2); }
    if (b0 + 3 < nb) { coff[b0 + 3] = p3; hc[b0 + 3] = p3; if (c3) gbase[b0 + 3] = atomicAdd(&cursor[b0 + 3], c3); }
    __syncthreads();

    // place records into LDS in bucket-sorted order
    #pragma unroll
    for (int j = 0; j < 16; ++j) {
        if (myb[j] >= 0) {
            int p = atomicAdd(&hc[myb[j]], 1);
            rec_s[p] = myrec[j];
            bkt_s[p] = (unsigned short)myb[j];
        }
    }
    __syncthreads();

    // grouped write-out: consecutive p within a bucket -> consecutive global dest
    int totv = min(4096, e - base);
    #pragma unroll
    for (int j = 0; j < 16; ++j) {
        int p = tid + j * 256;
        if (p < totv) {
            int b = bkt_s[p];
            int pos = gbase[b] + (p - coff[b]);
            if (pos < CAP) records[(size_t)b * CAP + pos] = rec_s[p];
        }
    }
}

// Per bucket: node-sort records into CSR (within the bucket's CAP window),
// emit offs/end/dinv. Reads & writes confined to ~8KB windows -> no amplification.
__global__ void csr_sort_kernel(const u32* __restrict__ records, const int* __restrict__ cursor,
                                int* __restrict__ csr, int* __restrict__ offs, int* __restrict__ endo,
                                float* __restrict__ dinv, int n) {
    __shared__ u32 rec_s[CAP];
    __shared__ int h[128], hx[128], hc[128];
    int tid = threadIdx.x, b = blockIdx.x;
    int cnt = min(cursor[b], CAP);
    const u32* rp = records + (size_t)b * CAP;
    if (tid < 128) h[tid] = 0;
    __syncthreads();
    for (int j = tid; j < cnt; j += 256) {
        u32 r = rp[j];
        rec_s[j] = r;
        atomicAdd(&h[r & 127], 1);
    }
    __syncthreads();
    if (tid < 128) hx[tid] = h[tid];
    __syncthreads();
    for (int off = 1; off < 128; off <<= 1) {
        int t = (tid < 128 && tid >= off) ? hx[tid - off] : 0;
        __syncthreads();
        if (tid < 128) hx[tid] += t;
        __syncthreads();
    }
    if (tid < 128) {
        int excl = hx[tid] - h[tid];
        hc[tid] = excl;
        int g = b * 128 + tid;
        if (g < n) {
            offs[g] = b * CAP + excl;
            endo[g] = b * CAP + excl + h[tid];
            dinv[g] = rsqrtf((float)(1 + h[tid]));
        }
    }
    __syncthreads();
    for (int j = tid; j < cnt; j += 256) {
        u32 r = rec_s[j];
        int p = atomicAdd(&hc[r & 127], 1);
        csr[(size_t)b * CAP + p] = (int)(r >> 7);
    }
}

// ts[node][c] = bf16( (in[node] @ W)[c] * dinv[node] ) via MFMA, fragment-direct.
// Wave = 32 nodes (2 row-tiles): latency-bound kernel, maximize wave count.
// f32in path additionally stores its A fragments (x bf16) to Axh cols 64..127.
__launch_bounds__(256, 2)
__global__ void matmul64_mfma_kernel(const float* __restrict__ inF, const u16* __restrict__ inB,
                                     const u16* __restrict__ Whi, const u16* __restrict__ Wlo,
                                     const float* __restrict__ dinv, u16* __restrict__ out,
                                     u16* __restrict__ Axh, int n, int f32in) {
    int tid = threadIdx.x;
    int wave = tid >> 6, lane = tid & 63;
    int l15 = lane & 15, lg = lane >> 4;
    int node0 = blockIdx.x * 128 + wave * 32;

    // A fragments: 2 row-tiles x 2 ksteps
    bf16x8 a[2][2];
    #pragma unroll
    for (int rt = 0; rt < 2; ++rt)
        #pragma unroll
        for (int s = 0; s < 2; ++s) {
            int row = node0 + rt * 16 + l15;
            bf16x8 av = (bf16x8){0, 0, 0, 0, 0, 0, 0, 0};
            if (row < n) {
                if (f32in) {
                    const float* p = inF + (size_t)row * 64 + s * 32 + lg * 8;
                    float4 v0 = *(const float4*)p;
                    float4 v1 = *(const float4*)(p + 4);
                    av[0] = (short)f2bf(v0.x); av[1] = (short)f2bf(v0.y);
                    av[2] = (short)f2bf(v0.z); av[3] = (short)f2bf(v0.w);
                    av[4] = (short)f2bf(v1.x); av[5] = (short)f2bf(v1.y);
                    av[6] = (short)f2bf(v1.z); av[7] = (short)f2bf(v1.w);
                } else {
                    av = *(const bf16x8*)(inB + (size_t)row * 64 + s * 32 + lg * 8);
                }
            }
            a[rt][s] = av;
        }

    // fold of xcvt: x fragments ARE the A cols 64..127 fragments; per-lane store
    // address is contiguous: ((nt*4 + 2 + s)*64 + lane)*8
    if (f32in) {
        #pragma unroll
        for (int rt = 0; rt < 2; ++rt)
            #pragma unroll
            for (int s = 0; s < 2; ++s) {
                size_t reg = ((size_t)((node0 >> 4) + rt) * 4 + 2 + s);
                *(bf16x8*)(Axh + (reg * 64 + lane) * 8) = a[rt][s];
            }
    }

    // B fragments: 4 col-tiles x 2 ksteps, hi+lo
    bf16x8 bh[4][2], bl[4][2];
    #pragma unroll
    for (int ct = 0; ct < 4; ++ct)
        #pragma unroll
        for (int s = 0; s < 2; ++s) {
            size_t off = (((size_t)(ct * 2 + s)) * 64 + lane) * 8;
            bh[ct][s] = *(const bf16x8*)(Whi + off);
            bl[ct][s] = *(const bf16x8*)(Wlo + off);
        }

    f32x4 acc[2][4];
    #pragma unroll
    for (int rt = 0; rt < 2; ++rt)
        #pragma unroll
        for (int ct = 0; ct < 4; ++ct) acc[rt][ct] = (f32x4){0.f, 0.f, 0.f, 0.f};

    #pragma unroll
    for (int s = 0; s < 2; ++s)
        #pragma unroll
        for (int rt = 0; rt < 2; ++rt)
            #pragma unroll
            for (int ct = 0; ct < 4; ++ct) {
                acc[rt][ct] = __builtin_amdgcn_mfma_f32_16x16x32_bf16(a[rt][s], bh[ct][s], acc[rt][ct], 0, 0, 0);
                acc[rt][ct] = __builtin_amdgcn_mfma_f32_16x16x32_bf16(a[rt][s], bl[ct][s], acc[rt][ct], 0, 0, 0);
            }

    // epilogue: scale by dinv, cvt bf16, store (C layout: col=l&15, row=lg*4+r)
    #pragma unroll
    for (int rt = 0; rt < 2; ++rt)
        #pragma unroll
        for (int r = 0; r < 4; ++r) {
            int node = node0 + rt * 16 + lg * 4 + r;
            if (node < n) {
                float dv = dinv[node];
                #pragma unroll
                for (int ct = 0; ct < 4; ++ct)
                    out[(size_t)node * 64 + ct * 16 + l15] = f2bf(acc[rt][ct][r] * dv);
            }
        }
}

// Vectorized gather agg: one wave per node; lane handles features 4*(l&15)..+3
// (uint2 = 4 bf16); the 4 sixteen-lane groups process 4 different edges per load.
// 16 edges (4 independent gathers) per iteration; tail lanes gather the
// pre-zeroed row n (no masking). Layer 1: relu, row-major bf16 out.
__global__ void agg4_csr_kernel(const int* __restrict__ csr, const int* __restrict__ offs,
                                const int* __restrict__ endo, const u16* __restrict__ ts,
                                const float* __restrict__ dinv, const float* __restrict__ bias,
                                u16* __restrict__ out, int n) {
    int node = blockIdx.x * 4 + (threadIdx.x >> 6);
    int lane = threadIdx.x & 63;
    int l15 = lane & 15, lg = lane >> 4;
    if (node >= n) return;
    int start = offs[node];
    int end = endo[node];
    const uint2* tsv = (const uint2*)ts;   // row = 16 uint2; row n is all-zero
    float a0 = 0.f, a1 = 0.f, a2 = 0.f, a3 = 0.f;
    for (int j = start; j < end; j += 64) {
        int cnt = min(64, end - j);
        int sidx = (lane < cnt) ? csr[j + lane] : n;   // tail -> zero row
        for (int jb = 0; jb < cnt; jb += 16) {
            int s0 = __shfl(sidx, jb + lg);
            int s1 = __shfl(sidx, jb + 4 + lg);
            int s2 = __shfl(sidx, jb + 8 + lg);
            int s3 = __shfl(sidx, jb + 12 + lg);
            uint2 w0 = tsv[(size_t)s0 * 16 + l15];
            uint2 w1 = tsv[(size_t)s1 * 16 + l15];
            uint2 w2 = tsv[(size_t)s2 * 16 + l15];
            uint2 w3 = tsv[(size_t)s3 * 16 + l15];
            a0 += (blo(w0.x) + blo(w1.x)) + (blo(w2.x) + blo(w3.x));
            a1 += (bhi(w0.x) + bhi(w1.x)) + (bhi(w2.x) + bhi(w3.x));
            a2 += (blo(w0.y) + blo(w1.y)) + (blo(w2.y) + blo(w3.y));
            a3 += (bhi(w0.y) + bhi(w1.y)) + (bhi(w2.y) + bhi(w3.y));
        }
    }
    a0 += __shfl_xor(a0, 16); a0 += __shfl_xor(a0, 32);
    a1 += __shfl_xor(a1, 16); a1 += __shfl_xor(a1, 32);
    a2 += __shfl_xor(a2, 16); a2 += __shfl_xor(a2, 32);
    a3 += __shfl_xor(a3, 16); a3 += __shfl_xor(a3, 32);
    uint2 sw = tsv[(size_t)node * 16 + l15];     // self-loop row
    a0 += blo(sw.x); a1 += bhi(sw.x); a2 += blo(sw.y); a3 += bhi(sw.y);
    float dv = dinv[node];
    float4 bv = *(const float4*)(bias + 4 * l15);
    float v0 = fmaxf(dv * a0 + bv.x, 0.f);
    float v1 = fmaxf(dv * a1 + bv.y, 0.f);
    float v2 = fmaxf(dv * a2 + bv.z, 0.f);
    float v3 = fmaxf(dv * a3 + bv.w, 0.f);
    if (lg == 0) {
        u32 p0 = ((u32)f2bf(v1) << 16) | (u32)f2bf(v0);
        u32 p1 = ((u32)f2bf(v3) << 16) | (u32)f2bf(v2);
        *(uint2*)(out + (size_t)node * 64 + l15 * 4) = make_uint2(p0, p1);
    }
}

// Layer 2 variant: no relu; writes bf16 in MFMA fragment order (A cols 0..63).
__global__ void agg4_csr_frag_kernel(const int* __restrict__ csr, const int* __restrict__ offs,
                                     const int* __restrict__ endo, const u16* __restrict__ ts,
                                     const float* __restrict__ dinv, const float* __restrict__ bias,
                                     u16* __restrict__ Ahi, int n) {
    int node = blockIdx.x * 4 + (threadIdx.x >> 6);
    int lane = threadIdx.x & 63;
    int l15 = lane & 15, lg = lane >> 4;
    if (node >= n) return;
    int start = offs[node];
    int end = endo[node];
    const uint2* tsv = (const uint2*)ts;
    float a0 = 0.f, a1 = 0.f, a2 = 0.f, a3 = 0.f;
    for (int j = start; j < end; j += 64) {
        int cnt = min(64, end - j);
        int sidx = (lane < cnt) ? csr[j + lane] : n;   // tail -> zero row
        for (int jb = 0; jb < cnt; jb += 16) {
            int s0 = __shfl(sidx, jb + lg);
            int s1 = __shfl(sidx, jb + 4 + lg);
            int s2 = __shfl(sidx, jb + 8 + lg);
            int s3 = __shfl(sidx, jb + 12 + lg);
            uint2 w0 = tsv[(size_t)s0 * 16 + l15];
            uint2 w1 = tsv[(size_t)s1 * 16 + l15];
            uint2 w2 = tsv[(size_t)s2 * 16 + l15];
            uint2 w3 = tsv[(size_t)s3 * 16 + l15];
            a0 += (blo(w0.x) + blo(w1.x)) + (blo(w2.x) + blo(w3.x));
            a1 += (bhi(w0.x) + bhi(w1.x)) + (bhi(w2.x) + bhi(w3.x));
            a2 += (blo(w0.y) + blo(w1.y)) + (blo(w2.y) + blo(w3.y));
            a3 += (bhi(w0.y) + bhi(w1.y)) + (bhi(w2.y) + bhi(w3.y));
        }
    }
    a0 += __shfl_xor(a0, 16); a0 += __shfl_xor(a0, 32);
    a1 += __shfl_xor(a1, 16); a1 += __shfl_xor(a1, 32);
    a2 += __shfl_xor(a2, 16); a2 += __shfl_xor(a2, 32);
    a3 += __shfl_xor(a3, 16); a3 += __shfl_xor(a3, 32);
    uint2 sw = tsv[(size_t)node * 16 + l15];
    a0 += blo(sw.x); a1 += bhi(sw.x); a2 += blo(sw.y); a3 += bhi(sw.y);
    float dv = dinv[node];
    float4 bv = *(const float4*)(bias + 4 * l15);
    float v0 = dv * a0 + bv.x;
    float v1 = dv * a1 + bv.y;
    float v2 = dv * a2 + bv.z;
    float v3 = dv * a3 + bv.w;
    if (lg == 0) {
        int nt = node >> 4, r15 = node & 15;
        size_t a = (((size_t)nt * 4 + (l15 >> 3)) * 64 + ((l15 >> 1) & 3) * 16 + r15) * 8 + 4 * (l15 & 1);
        u32 p0 = ((u32)f2bf(v1) << 16) | (u32)f2bf(v0);
        u32 p1 = ((u32)f2bf(v3) << 16) | (u32)f2bf(v2);
        *(uint2*)(Ahi + a) = make_uint2(p0, p1);
    }
}

__device__ __forceinline__ void loadW6(const u16* __restrict__ Whi,
                                       int t0, int s, int lane, bf16x8 (&bh)[4]) {
    #pragma unroll
    for (int ct = 0; ct < 4; ++ct) {
        size_t off = (((size_t)(t0 + ct) * 4 + s) * 64 + lane) * 8;
        bh[ct] = *(const bf16x8*)(Whi + off);
    }
}

// MLP head v6 (proven best; v7/v8/v9 all lost to occupancy or compiler W-remat):
// block = 256 nodes (4 waves x 64 nodes), all 512 cols.
// A bf16 in LDS (64 KB); W plain bf16 double-buffered from L2.
__launch_bounds__(256, 2)
__global__ void mlp_mfma6_kernel(const u16* __restrict__ Ahi, const u16* __restrict__ Whi,
                                 const float* __restrict__ bp1, const float* __restrict__ Wp2,
                                 const float* __restrict__ bp2, float* __restrict__ out, int n) {
    __shared__ __align__(16) u16 a_s[32768];    // 64 KB: 64 regions x 512 u16
    __shared__ __align__(16) float b1lds[512];
    __shared__ __align__(16) float w2lds[512 * 3];
    int tid = threadIdx.x;

    // stage A slice (contiguous in fragment-linear order)
    size_t gbase = (size_t)blockIdx.x * 32768;
    #pragma unroll
    for (int i = 0; i < 16; ++i) {
        int idx = i * 2048 + tid * 8;
        *(bf16x8*)&a_s[idx] = *(const bf16x8*)(Ahi + gbase + idx);
    }
    b1lds[tid] = bp1[tid];
    b1lds[tid + 256] = bp1[tid + 256];
    #pragma unroll
    for (int i = 0; i < 6; ++i) w2lds[tid + i * 256] = Wp2[tid + i * 256];
    __syncthreads();

    int wave = tid >> 6, lane = tid & 63;
    int l15 = lane & 15, l4 = lane >> 4;
    int node0 = blockIdx.x * 256 + wave * 64;

    float pr[4][4][3];
    #pragma unroll
    for (int rt = 0; rt < 4; ++rt)
        #pragma unroll
        for (int r = 0; r < 4; ++r) { pr[rt][r][0] = 0.f; pr[rt][r][1] = 0.f; pr[rt][r][2] = 0.f; }

    bf16x8 bhE[4], bhO[4];
    loadW6(Whi, 0, 0, lane, bhE);

#define MFMA_S(S, BH)                                                                      \
    do {                                                                                   \
        _Pragma("unroll")                                                                  \
        for (int rt = 0; rt < 4; ++rt) {                                                   \
            bf16x8 a = *(const bf16x8*)&a_s[(wave * 16 + rt * 4 + (S)) * 512 + lane * 8];  \
            _Pragma("unroll")                                                              \
            for (int ct = 0; ct < 4; ++ct)                                                 \
                acc[rt][ct] = __builtin_amdgcn_mfma_f32_16x16x32_bf16(a, BH[ct], acc[rt][ct], 0, 0, 0); \
        }                                                                                  \
    } while (0)

    for (int cg = 0; cg < 8; ++cg) {
        f32x4 acc[4][4];
        #pragma unroll
        for (int rt = 0; rt < 4; ++rt)
            #pragma unroll
            for (int ct = 0; ct < 4; ++ct) acc[rt][ct] = (f32x4){0.f, 0.f, 0.f, 0.f};

        int t0 = cg * 4;
        loadW6(Whi, t0, 1, lane, bhO);
        MFMA_S(0, bhE);
        loadW6(Whi, t0, 2, lane, bhE);
        MFMA_S(1, bhO);
        loadW6(Whi, t0, 3, lane, bhO);
        MFMA_S(2, bhE);
        loadW6(Whi, ((cg + 1) & 7) * 4, 0, lane, bhE);   // wraps to cg=0, harmless
        MFMA_S(3, bhO);

        // fold this col-group into per-lane partials
        #pragma unroll
        for (int ct = 0; ct < 4; ++ct) {
            int c = (t0 + ct) * 16 + l15;
            float b1v = b1lds[c];
            float w20 = w2lds[c * 3 + 0], w21 = w2lds[c * 3 + 1], w22 = w2lds[c * 3 + 2];
            #pragma unroll
            for (int rt = 0; rt < 4; ++rt)
                #pragma unroll
                for (int r = 0; r < 4; ++r) {
                    float h = fmaxf(acc[rt][ct][r] + b1v, 0.f);
                    pr[rt][r][0] = fmaf(h, w20, pr[rt][r][0]);
                    pr[rt][r][1] = fmaf(h, w21, pr[rt][r][1]);
                    pr[rt][r][2] = fmaf(h, w22, pr[rt][r][2]);
                }
        }
    }
#undef MFMA_S

    float c0 = bp2[0], c1 = bp2[1], c2 = bp2[2];
    #pragma unroll
    for (int rt = 0; rt < 4; ++rt)
        #pragma unroll
        for (int r = 0; r < 4; ++r)
            #pragma unroll
            for (int j = 0; j < 3; ++j) {
                float v = pr[rt][r][j];
                v += __shfl_xor(v, 1);
                v += __shfl_xor(v, 2);
                v += __shfl_xor(v, 4);
                v += __shfl_xor(v, 8);
                pr[rt][r][j] = v;
            }
    if (l15 == 0) {
        #pragma unroll
        for (int rt = 0; rt < 4; ++rt)
            #pragma unroll
            for (int r = 0; r < 4; ++r) {
                int node = node0 + rt * 16 + l4 * 4 + r;
                if (node < n) {
                    out[(size_t)node * 3 + 0] = pr[rt][r][0] + c0;
                    out[(size_t)node * 3 + 1] = pr[rt][r][1] + c1;
                    out[(size_t)node * 3 + 2] = pr[rt][r][2] + c2;
                }
            }
    }
}

extern "C" void kernel_launch(void* const* d_in, const int* in_sizes, int n_in,
                              void* d_out, int out_size, void* d_ws, size_t ws_size,
                              hipStream_t stream) {
    const float* x   = (const float*)d_in[0];
    const int*   ei  = (const int*)d_in[1];   // [2][E]
    const float* W1  = (const float*)d_in[2];
    const float* b1  = (const float*)d_in[3];
    const float* W2  = (const float*)d_in[4];
    const float* b2  = (const float*)d_in[5];
    const float* Wp1 = (const float*)d_in[6];
    const float* bp1 = (const float*)d_in[7];
    const float* Wp2 = (const float*)d_in[8];
    const float* bp2 = (const float*)d_in[9];
    float* out = (float*)d_out;

    const int n = in_sizes[0] / 64;
    const int e = in_sizes[1] / 2;
    const int pad_n = (n + 255) & ~255;      // mlp block = 256 nodes
    const int nb = (n + 127) >> 7;           // 128-node buckets
    const int* src = ei;
    const int* dst = ei + e;

    char* ws = (char*)d_ws;
    size_t o = 0;
    int* cursor = (int*)(ws + o);            o += ((size_t)nb * 4 + 511) & ~(size_t)511;
    int* offs   = (int*)(ws + o);            o += ((size_t)n * 4 + 511) & ~(size_t)511;
    int* endo   = (int*)(ws + o);            o += ((size_t)n * 4 + 511) & ~(size_t)511;
    float* dinv = (float*)(ws + o);          o += ((size_t)n * 4 + 511) & ~(size_t)511;
    u32* records = (u32*)(ws + o);           o += ((size_t)nb * CAP * 4 + 511) & ~(size_t)511;
    int* csr    = (int*)(ws + o);            o += ((size_t)nb * CAP * 4 + 511) & ~(size_t)511;
    u16* tsbuf  = (u16*)(ws + o);            o += ((size_t)(pad_n + 256) * 64 * 2 + 511) & ~(size_t)511;  // +1 zero row
    u16* h1b    = (u16*)(ws + o);            o += ((size_t)pad_n * 64 * 2 + 511) & ~(size_t)511;
    u16* Ahi    = (u16*)(ws + o);            o += ((size_t)pad_n * 128 * 2 + 511) & ~(size_t)511;
    u16* Whi    = (u16*)(ws + o);            o += 512 * 128 * 2;
    u16* W1hi   = (u16*)(ws + o);            o += 64 * 64 * 2;
    u16* W1lo   = (u16*)(ws + o);            o += 64 * 64 * 2;
    u16* W2hi   = (u16*)(ws + o);            o += 64 * 64 * 2;
    u16* W2lo   = (u16*)(ws + o);            o += 64 * 64 * 2;

    // ----- merged preprocessing: cursor/zrow zero + all weight conversions -----
    hipLaunchKernelGGL(prep_kernel, dim3(40), dim3(256), 0, stream,
                       cursor, nb, tsbuf + (size_t)n * 64,
                       Wp1, Whi, W1, W1hi, W1lo, W2, W2hi, W2lo);
    hipLaunchKernelGGL(binfill_kernel, dim3((e + 4095) / 4096), dim3(256), 0, stream,
                       src, dst, cursor, records, e, nb);
    hipLaunchKernelGGL(csr_sort_kernel, dim3(nb), dim3(256), 0, stream,
                       records, cursor, csr, offs, endo, dinv, n);

    // ----- GCN layer 1: ts1 = bf16((x @ W1) * dinv); also emits x -> Ahi cols 64..127 -----
    hipLaunchKernelGGL(matmul64_mfma_kernel, dim3(pad_n / 128), dim3(256), 0, stream,
                       x, (const u16*)nullptr, W1hi, W1lo, dinv, tsbuf, Ahi, n, 1);
    hipLaunchKernelGGL(agg4_csr_kernel, dim3((n + 3) / 4), dim3(256), 0, stream,
                       csr, offs, endo, tsbuf, dinv, b1, h1b, n);

    // ----- GCN layer 2: ts2 = bf16((h1 @ W2) * dinv); agg writes bf16 A cols 0..63 -----
    hipLaunchKernelGGL(matmul64_mfma_kernel, dim3(pad_n / 128), dim3(256), 0, stream,
                       (const float*)nullptr, h1b, W2hi, W2lo, dinv, tsbuf, (u16*)nullptr, n, 0);
    hipLaunchKernelGGL(agg4_csr_frag_kernel, dim3((n + 3) / 4), dim3(256), 0, stream,
                       csr, offs, endo, tsbuf, dinv, b2, Ahi, n);

    // ----- MLP head (LDS-A bf16, bf16 W, MFMA) -----
    hipLaunchKernelGGL(mlp_mfma6_kernel, dim3(pad_n / 256), dim3(256), 0, stream,
                       Ahi, Whi, bp1, Wp2, bp2, out, n);
}